// Round 1
// baseline (445.838 us; speedup 1.0000x reference)
//
#include <hip/hip_runtime.h>

// out[b,n,m,f] = e0 + e1 * tanh((z - e2) * e3), params gathered per (b,f).
// B=16, N=8, M=1024, F=512. Memory-bound: 256 MiB in + 256 MiB out.
//
// Each thread: fixed (b, f0..f0+3), loops over 64 rows of the n*m=8192 row
// space so the param gather is amortized. Inner loop = float4 load/store only.

__device__ __forceinline__ float fast_tanh(float x) {
    // tanh(x) = sign(x) * (1 - e^{-2|x|}) / (1 + e^{-2|x|}); exact saturation
    // for large |x| (t -> 0), exact 0 at x=0. __expf ~2ulp, well within the
    // 5.3e-2 absmax threshold.
    float ax = __builtin_fabsf(x);
    float t  = __expf(-2.0f * ax);
    float r  = __fdividef(1.0f - t, 1.0f + t);
    return __builtin_copysignf(r, x);
}

__global__ __launch_bounds__(256, 4)
void TanhRT_45406394253467_kernel(const float* __restrict__ z,
                                  const int* __restrict__ mask,
                                  const float* __restrict__ eta,
                                  float* __restrict__ out) {
    const int tid   = threadIdx.x;       // 0..255
    const int fg    = tid & 127;         // f-group: f0 = fg*4 (covers F=512)
    const int rsub  = tid >> 7;          // 0 or 1: which of 2 rows per iter
    const int b     = blockIdx.y;        // 0..15
    const int chunk = blockIdx.x;        // 0..127, each chunk = 64 rows

    const int f0 = fg << 2;

    // Gather per-f params once; reused over all 64 rows this thread touches.
    float4 E0, E1, E2, E3;
    const int mbase = b * 512 + f0;
    float* e0p = (float*)&E0;
    float* e1p = (float*)&E1;
    float* e2p = (float*)&E2;
    float* e3p = (float*)&E3;
#pragma unroll
    for (int j = 0; j < 4; ++j) {
        const int m = mask[mbase + j];             // 0..12, L1/L2-hot (32 KiB)
        const float4 p = ((const float4*)eta)[m];  // 13x16B, L1-hot
        e0p[j] = p.x; e1p[j] = p.y; e2p[j] = p.z; e3p[j] = p.w;
    }

    // Row space: n*m = 8192 rows per b, each row 512 floats.
    const size_t row0 = (size_t)b * 8192 + (size_t)chunk * 64 + (size_t)rsub;
    const float4* zp = (const float4*)(z + row0 * 512 + f0);
    float4*       op = (float4*)(out + row0 * 512 + f0);
    // 2 rows per iteration (rsub splits them) -> stride 2*512 floats = 256 float4.

#pragma unroll 4
    for (int it = 0; it < 32; ++it) {
        const float4 v = zp[(size_t)it * 256];
        float4 r;
        r.x = E0.x + E1.x * fast_tanh((v.x - E2.x) * E3.x);
        r.y = E0.y + E1.y * fast_tanh((v.y - E2.y) * E3.y);
        r.z = E0.z + E1.z * fast_tanh((v.z - E2.z) * E3.z);
        r.w = E0.w + E1.w * fast_tanh((v.w - E2.w) * E3.w);
        op[(size_t)it * 256] = r;
    }
}

extern "C" void kernel_launch(void* const* d_in, const int* in_sizes, int n_in,
                              void* d_out, int out_size, void* d_ws, size_t ws_size,
                              hipStream_t stream) {
    const float* z    = (const float*)d_in[0];
    const int*   mask = (const int*)d_in[1];
    const float* eta  = (const float*)d_in[2];
    float*       out  = (float*)d_out;

    dim3 grid(128, 16);   // 128 row-chunks x 16 batches
    dim3 block(256);
    TanhRT_45406394253467_kernel<<<grid, block, 0, stream>>>(z, mask, eta, out);
}

// Round 2
// 430.843 us; speedup vs baseline: 1.0348x; 1.0348x over previous
//
#include <hip/hip_runtime.h>

// out[b,n,m,f] = e0 + e1 * tanh((z - e2) * e3), params gathered per (b,f).
// B=16, N=8, M=1024, F=512. Memory-bound: 256 MiB in + 256 MiB out,
// floor ~82 us @ 6.5 TB/s (rate demonstrated by harness fill kernels).
//
// tanh(x) = 1 - 2/(exp2(x*2/ln2)+1): branch-free, no abs/copysign needed
// (exp2 -> inf gives +1, -> 0 gives -1; exact saturation). With per-thread
// constant folding the whole element is: fma, exp2, add, rcp, fma
// (3 VALU + 2 transcendental) -> ~37 us chip-wide VALU, hidden under the
// memory stream.

typedef float vf4 __attribute__((ext_vector_type(4)));

__global__ __launch_bounds__(256, 4)
void TanhRT_45406394253467_kernel(const float* __restrict__ z,
                                  const int* __restrict__ mask,
                                  const float* __restrict__ eta,
                                  float* __restrict__ out) {
    const int tid   = threadIdx.x;       // 0..255
    const int fg    = tid & 127;         // f-group: f0 = fg*4 (covers F=512)
    const int rsub  = tid >> 7;          // 0 or 1: which of 2 rows per iter
    const int b     = blockIdx.y;        // 0..15
    const int chunk = blockIdx.x;        // 0..127, each chunk = 64 rows

    const int f0 = fg << 2;

    // Per-thread folded params, reused over all 64 rows this thread touches.
    //   arg2 = (z - e2)*e3*(2/ln2) = fma(z, A, B)
    //   out  = (e0+e1) + (-2*e1) * rcp(1 + exp2(arg2))
    const float C = 2.8853900817779268f;  // 2/ln(2)
    vf4 A, Bv, S, T;
    const int mbase = b * 512 + f0;
#pragma unroll
    for (int j = 0; j < 4; ++j) {
        const int m = mask[mbase + j];             // 0..12, L1/L2-hot (32 KiB)
        const float4 p = ((const float4*)eta)[m];  // {e0,e1,e2,e3}, 13x16B, L1-hot
        A[j] = p.w * C;
        Bv[j] = -(p.z * p.w * C);
        S[j] = p.x + p.y;
        T[j] = -2.0f * p.y;
    }

    // Row space: n*m = 8192 rows per b, each row 512 floats.
    // Block streams a contiguous 128 KiB region (64 rows); per iteration the
    // 4 waves cover 4 KiB contiguous (2 rows), stride 4 KiB between iters.
    const size_t row0 = (size_t)b * 8192 + (size_t)chunk * 64 + (size_t)rsub;
    const vf4* zp = (const vf4*)(z + row0 * 512 + f0);
    vf4*       op = (vf4*)(out + row0 * 512 + f0);

#pragma unroll 8
    for (int it = 0; it < 32; ++it) {
        const vf4 v = __builtin_nontemporal_load(zp + (size_t)it * 256);
        vf4 r;
        r.x = __builtin_fmaf(T.x, __builtin_amdgcn_rcpf(1.0f + __builtin_amdgcn_exp2f(__builtin_fmaf(v.x, A.x, Bv.x))), S.x);
        r.y = __builtin_fmaf(T.y, __builtin_amdgcn_rcpf(1.0f + __builtin_amdgcn_exp2f(__builtin_fmaf(v.y, A.y, Bv.y))), S.y);
        r.z = __builtin_fmaf(T.z, __builtin_amdgcn_rcpf(1.0f + __builtin_amdgcn_exp2f(__builtin_fmaf(v.z, A.z, Bv.z))), S.z);
        r.w = __builtin_fmaf(T.w, __builtin_amdgcn_rcpf(1.0f + __builtin_amdgcn_exp2f(__builtin_fmaf(v.w, A.w, Bv.w))), S.w);
        __builtin_nontemporal_store(r, op + (size_t)it * 256);
    }
}

extern "C" void kernel_launch(void* const* d_in, const int* in_sizes, int n_in,
                              void* d_out, int out_size, void* d_ws, size_t ws_size,
                              hipStream_t stream) {
    const float* z    = (const float*)d_in[0];
    const int*   mask = (const int*)d_in[1];
    const float* eta  = (const float*)d_in[2];
    float*       out  = (float*)d_out;

    dim3 grid(128, 16);   // 128 row-chunks x 16 batches
    dim3 block(256);
    TanhRT_45406394253467_kernel<<<grid, block, 0, stream>>>(z, mask, eta, out);
}